// Round 15
// baseline (313.716 us; speedup 1.0000x reference)
//
#include <hip/hip_runtime.h>
#include <hip/hip_fp16.h>
#include <hip/hip_cooperative_groups.h>
#include <type_traits>

namespace cg = cooperative_groups;

#define NFEAT 128
// Packed bucket entry: (dst & 255) << 17 | src  (src < 2^17, bucket-local dst 8 bits)
#define SRC_BITS 17
#define SRC_MASK ((1u << SRC_BITS) - 1u)
#define BUKSH 8        // 256-node buckets
#define CHUNK 8192     // edges per sort block
#define KG 32          // sort blocks per scan group

using f16x8 = __attribute__((ext_vector_type(8))) _Float16;
using f32x4 = __attribute__((ext_vector_type(4))) float;

static inline size_t align_up(size_t x, size_t a) { return (x + a - 1) & ~(a - 1); }

// ---------------- fused preprocessing (cooperative): wt2 + hist + colscan + scatter + CSR ----------------
// grid = nblk blocks x 512 threads (co-resident; nblk=196 <= 256 CUs).

__global__ __launch_bounds__(512) void k_prep(const float* __restrict__ W1,
                                              const float* __restrict__ W2,
                                              __half* __restrict__ W1t,
                                              __half* __restrict__ W2t,
                                              const int* __restrict__ src,
                                              const int* __restrict__ dst,
                                              int* __restrict__ gh,
                                              int* __restrict__ psum,
                                              int* __restrict__ rsB,
                                              int* __restrict__ rs,
                                              float* __restrict__ dis,
                                              unsigned* __restrict__ ebuf,
                                              int* __restrict__ csrc,
                                              int NBUK, int nblk, int NG, int N, int E) {
  cg::grid_group grid = cg::this_grid();
  extern __shared__ int lds[];   // >= 768 ints
  const int tid = threadIdx.x;
  const int bid = blockIdx.x;
  const int nb = gridDim.x;

  // phase 0a: weight transpose to fp16 (first 32768 global work items)
  {
    int g = bid * 512 + tid;
    if (g < 32768) {
      int m = g >> 14;
      int oo = g & 16383;
      const float* W = m ? W2 : W1;
      __half* Wt = m ? W2t : W1t;
      int cdst = oo >> 7, rdst = oo & 127;
      Wt[oo] = __float2half(W[rdst * 128 + cdst]);
    }
  }
  // phase 0b: per-block LDS histogram over buckets
  {
    for (int i = tid; i < NBUK; i += 512) lds[i] = 0;
    __syncthreads();
    int base = bid * CHUNK;
    int end = min(base + CHUNK, E);
    for (int e = base + tid; e < end; e += 512)
      atomicAdd(&lds[dst[e] >> BUKSH], 1);
    __syncthreads();
    int* outp = gh + (size_t)bid * NBUK;
    for (int i = tid; i < NBUK; i += 512) outp[i] = lds[i];
  }
  grid.sync();

  // phase 1: within-group block prefix (NG*NBUK work items)
  {
    int t = bid * 512 + tid;
    if (t < NG * NBUK) {
      int kg = t / NBUK;
      int b = t - kg * NBUK;
      int k0 = kg * KG, k1 = min(k0 + KG, nblk);
      int run = 0;
      for (int k = k0; k < k1; ++k) {
        int idx = k * NBUK + b;
        int c = gh[idx];
        gh[idx] = run;
        run += c;
      }
      psum[kg * NBUK + b] = run;
    }
  }
  grid.sync();

  // phase 2: group-sum scan per bucket + bucket-base scan (block 0; NBUK <= 512)
  if (bid == 0) {
    __shared__ int sd[512];
    int b = tid;
    int tot = 0;
    if (b < NBUK) {
      int run = 0;
      for (int kg = 0; kg < NG; ++kg) {
        int idx = kg * NBUK + b;
        int c = psum[idx];
        psum[idx] = run;
        run += c;
      }
      tot = run;
    }
    sd[b] = tot;
    __syncthreads();
    for (int off = 1; off < 512; off <<= 1) {
      int t2 = (b >= off) ? sd[b - off] : 0;
      __syncthreads();
      sd[b] += t2;
      __syncthreads();
    }
    if (b < NBUK) rsB[b] = sd[b] - tot;
    if (b == 0) rsB[NBUK] = E;
  }
  grid.sync();

  // phase 3: scatter packed edges into bucket-sorted ebuf (LDS cursors)
  {
    const int* g = gh + (size_t)bid * NBUK;
    const int* p = psum + (size_t)(bid / KG) * NBUK;
    for (int i = tid; i < NBUK; i += 512) lds[i] = rsB[i] + p[i] + g[i];
    __syncthreads();
    int base = bid * CHUNK;
    int end = min(base + CHUNK, E);
    for (int e = base + tid; e < end; e += 512) {
      int d = dst[e];
      int pos = atomicAdd(&lds[d >> BUKSH], 1);
      ebuf[pos] = (unsigned)src[e] | ((unsigned)(d & 255) << SRC_BITS);
    }
  }
  grid.sync();

  // phase 4: per-bucket CSR build (buckets strided across blocks)
  for (int b = bid; b < NBUK; b += nb) {
    int* hist = lds;
    int* curs = lds + 256;
    int* sd2  = lds + 512;
    int node0 = b << BUKSH;
    int nn = min(256, N - node0);
    int base = rsB[b], end = rsB[b + 1];
    __syncthreads();  // protect lds reuse across iterations
    if (tid < 256) hist[tid] = 0;
    __syncthreads();
    for (int e = base + tid; e < end; e += 512)
      atomicAdd(&hist[ebuf[e] >> SRC_BITS], 1);
    __syncthreads();
    if (tid < 256) sd2[tid] = hist[tid];
    __syncthreads();
    for (int off = 1; off < 256; off <<= 1) {
      int t2 = 0;
      if (tid < 256 && tid >= off) t2 = sd2[tid - off];
      __syncthreads();
      if (tid < 256) sd2[tid] += t2;
      __syncthreads();
    }
    if (tid < 256) {
      int c = hist[tid];
      int start = base + sd2[tid] - c;  // exclusive prefix
      curs[tid] = start;
      hist[tid] = start;
    }
    __syncthreads();
    if (tid < nn) {
      int start = hist[tid];
      int nxt = (tid == nn - 1) ? end : hist[tid + 1];
      rs[node0 + tid] = start;
      dis[node0 + tid] = rsqrtf((float)(nxt - start) + 1.0f);
    }
    if (tid == 0) rs[node0 + nn] = end;  // rs[N]=E on last bucket; benign dup otherwise
    for (int e = base + tid; e < end; e += 512) {
      unsigned u = ebuf[e];
      int pos = atomicAdd(&curs[u >> SRC_BITS], 1);
      csrc[pos] = (int)(u & SRC_MASK);
    }
  }
}

// ---------------- MFMA GEMM: P[N x128] = dis[i]*(X @ W), fp16 frag, fp32 acc ----------------

#define XS_LD 136  // halves; 272B row stride -> 2-way (free) bank aliasing on b128

template <typename T>
__global__ __launch_bounds__(256) void k_gemm(const T* __restrict__ X,
                                              const __half* __restrict__ Wt,
                                              const float* __restrict__ dis,
                                              __half* __restrict__ P, int N) {
  __shared__ __half Xs[64 * XS_LD];
  __shared__ __half Ws[128 * XS_LD];
  const int tid = threadIdx.x;
  const int wave = tid >> 6, lane = tid & 63;
  const int l15 = lane & 15, g = lane >> 4;
  const int rowBase = blockIdx.x * 64;

  #pragma unroll
  for (int it = 0; it < 8; ++it) {
    int q = it * 256 + tid;
    int r = q >> 4, c = (q & 15) * 8;
    *(int4*)&Ws[r * XS_LD + c] = *(const int4*)(Wt + r * 128 + c);
  }
  if constexpr (std::is_same_v<T, float>) {
    #pragma unroll
    for (int it = 0; it < 8; ++it) {
      int q = it * 256 + tid;
      int r = q >> 5, c = (q & 31) * 4;
      int gr = rowBase + r;
      float4 v = make_float4(0.f, 0.f, 0.f, 0.f);
      if (gr < N) v = *(const float4*)(X + (size_t)gr * NFEAT + c);
      __half2 pk[2];
      pk[0] = __floats2half2_rn(v.x, v.y);
      pk[1] = __floats2half2_rn(v.z, v.w);
      *(uint2*)&Xs[r * XS_LD + c] = *(uint2*)pk;
    }
  } else {
    #pragma unroll
    for (int it = 0; it < 4; ++it) {
      int q = it * 256 + tid;
      int r = q >> 4, c = (q & 15) * 8;
      int gr = rowBase + r;
      int4 v = make_int4(0, 0, 0, 0);
      if (gr < N) v = *(const int4*)(X + (size_t)gr * NFEAT + c);
      *(int4*)&Xs[r * XS_LD + c] = v;
    }
  }
  __syncthreads();

  f32x4 acc[4][2];
  #pragma unroll
  for (int rt = 0; rt < 4; ++rt) {
    acc[rt][0] = (f32x4)(0.f);
    acc[rt][1] = (f32x4)(0.f);
  }
  const int koff = g * 8;
  const int c0 = (wave * 2) * 16 + l15;
  const int c1 = (wave * 2 + 1) * 16 + l15;

  #pragma unroll
  for (int ks = 0; ks < 4; ++ks) {
    int kb = ks * 32 + koff;
    f16x8 b0 = *(const f16x8*)&Ws[c0 * XS_LD + kb];
    f16x8 b1 = *(const f16x8*)&Ws[c1 * XS_LD + kb];
    #pragma unroll
    for (int rt = 0; rt < 4; ++rt) {
      f16x8 a = *(const f16x8*)&Xs[(rt * 16 + l15) * XS_LD + kb];
      acc[rt][0] = __builtin_amdgcn_mfma_f32_16x16x32_f16(a, b0, acc[rt][0], 0, 0, 0);
      acc[rt][1] = __builtin_amdgcn_mfma_f32_16x16x32_f16(a, b1, acc[rt][1], 0, 0, 0);
    }
  }

  const int colb = wave * 32 + l15;
  #pragma unroll
  for (int rt = 0; rt < 4; ++rt) {
    #pragma unroll
    for (int r = 0; r < 4; ++r) {
      int row = rowBase + rt * 16 + g * 4 + r;
      if (row < N) {
        float di = dis[row];
        P[(size_t)row * NFEAT + colb]      = __float2half(di * acc[rt][0][r]);
        P[(size_t)row * NFEAT + colb + 16] = __float2half(di * acc[rt][1][r]);
      }
    }
  }
}

// ---------------- aggregation: one wave/node, 4 groups x 16 lanes, 4 edges in flight ----------------

__device__ __forceinline__ float agg_body_h4(const __half* __restrict__ P,
                                             const int* __restrict__ rs,
                                             const int* __restrict__ csrc,
                                             int w, int g, int li, float facc[8]) {
  int e0 = rs[w], e1 = rs[w + 1];
  float di = rsqrtf((float)(e1 - e0) + 1.0f);
  __half2 a0 = __float2half2_rn(0.f), a1 = a0, a2 = a0, a3 = a0;
  __half2 c0 = a0, c1 = a0, c2 = a0, c3 = a0;
  if (g == 0) {  // self loop
    int4 raw = *(const int4*)(P + (size_t)w * NFEAT + li * 8);
    const __half2* h2 = (const __half2*)&raw;
    a0 = h2[0]; a1 = h2[1]; a2 = h2[2]; a3 = h2[3];
  }
  const int lastc = max(e1 - 1, 0);
  int e = e0 + g;
  int s0 = csrc[min(e, lastc)];
  int s1 = csrc[min(e + 4, lastc)];
  int s2 = csrc[min(e + 8, lastc)];
  int s3 = csrc[min(e + 12, lastc)];
  while (e + 12 < e1) {
    int4 r0 = *(const int4*)(P + (size_t)s0 * NFEAT + li * 8);
    int4 r1 = *(const int4*)(P + (size_t)s1 * NFEAT + li * 8);
    int4 r2 = *(const int4*)(P + (size_t)s2 * NFEAT + li * 8);
    int4 r3 = *(const int4*)(P + (size_t)s3 * NFEAT + li * 8);
    e += 16;
    s0 = csrc[min(e, lastc)];
    s1 = csrc[min(e + 4, lastc)];
    s2 = csrc[min(e + 8, lastc)];
    s3 = csrc[min(e + 12, lastc)];
    const __half2* h0 = (const __half2*)&r0;
    const __half2* h1 = (const __half2*)&r1;
    const __half2* h2 = (const __half2*)&r2;
    const __half2* h3 = (const __half2*)&r3;
    a0 = __hadd2(a0, h0[0]); a1 = __hadd2(a1, h0[1]);
    a2 = __hadd2(a2, h0[2]); a3 = __hadd2(a3, h0[3]);
    c0 = __hadd2(c0, h1[0]); c1 = __hadd2(c1, h1[1]);
    c2 = __hadd2(c2, h1[2]); c3 = __hadd2(c3, h1[3]);
    a0 = __hadd2(a0, h2[0]); a1 = __hadd2(a1, h2[1]);
    a2 = __hadd2(a2, h2[2]); a3 = __hadd2(a3, h2[3]);
    c0 = __hadd2(c0, h3[0]); c1 = __hadd2(c1, h3[1]);
    c2 = __hadd2(c2, h3[2]); c3 = __hadd2(c3, h3[3]);
  }
  if (e < e1) {
    int4 r = *(const int4*)(P + (size_t)s0 * NFEAT + li * 8);
    const __half2* h = (const __half2*)&r;
    a0 = __hadd2(a0, h[0]); a1 = __hadd2(a1, h[1]);
    a2 = __hadd2(a2, h[2]); a3 = __hadd2(a3, h[3]);
    e += 4;
  }
  if (e < e1) {
    int4 r = *(const int4*)(P + (size_t)s1 * NFEAT + li * 8);
    const __half2* h = (const __half2*)&r;
    c0 = __hadd2(c0, h[0]); c1 = __hadd2(c1, h[1]);
    c2 = __hadd2(c2, h[2]); c3 = __hadd2(c3, h[3]);
    e += 4;
  }
  if (e < e1) {
    int4 r = *(const int4*)(P + (size_t)s2 * NFEAT + li * 8);
    const __half2* h = (const __half2*)&r;
    a0 = __hadd2(a0, h[0]); a1 = __hadd2(a1, h[1]);
    a2 = __hadd2(a2, h[2]); a3 = __hadd2(a3, h[3]);
  }
  a0 = __hadd2(a0, c0); a1 = __hadd2(a1, c1);
  a2 = __hadd2(a2, c2); a3 = __hadd2(a3, c3);
  float2 f0 = __half22float2(a0), f1 = __half22float2(a1);
  float2 f2 = __half22float2(a2), f3 = __half22float2(a3);
  facc[0] = f0.x; facc[1] = f0.y; facc[2] = f1.x; facc[3] = f1.y;
  facc[4] = f2.x; facc[5] = f2.y; facc[6] = f3.x; facc[7] = f3.y;
  #pragma unroll
  for (int j = 0; j < 8; ++j) {
    float v = facc[j];
    v += __shfl_xor(v, 16, 64);
    v += __shfl_xor(v, 32, 64);
    facc[j] = v;
  }
  return di;
}

__global__ __launch_bounds__(256) void k_agg_relu(const __half* __restrict__ P,
                                                  const int* __restrict__ rs,
                                                  const int* __restrict__ csrc,
                                                  const float* __restrict__ bias,
                                                  __half* __restrict__ Hout, int N) {
  int w = (blockIdx.x * 256 + threadIdx.x) >> 6;
  if (w >= N) return;
  int lane = threadIdx.x & 63;
  int g = lane >> 4, li = lane & 15;
  float acc[8];
  float di = agg_body_h4(P, rs, csrc, w, g, li, acc);
  if (g == 0) {
    float4 b0 = *(const float4*)(bias + li * 8);
    float4 b1 = *(const float4*)(bias + li * 8 + 4);
    __half2 o[4];
    o[0] = __floats2half2_rn(fmaxf(fmaf(di, acc[0], b0.x), 0.f),
                             fmaxf(fmaf(di, acc[1], b0.y), 0.f));
    o[1] = __floats2half2_rn(fmaxf(fmaf(di, acc[2], b0.z), 0.f),
                             fmaxf(fmaf(di, acc[3], b0.w), 0.f));
    o[2] = __floats2half2_rn(fmaxf(fmaf(di, acc[4], b1.x), 0.f),
                             fmaxf(fmaf(di, acc[5], b1.y), 0.f));
    o[3] = __floats2half2_rn(fmaxf(fmaf(di, acc[6], b1.z), 0.f),
                             fmaxf(fmaf(di, acc[7], b1.w), 0.f));
    *(int4*)(Hout + (size_t)w * NFEAT + li * 8) = *(const int4*)o;
  }
}

__global__ __launch_bounds__(256) void k_agg_readout(const __half* __restrict__ P,
                                                     const int* __restrict__ rs,
                                                     const int* __restrict__ csrc,
                                                     const float* __restrict__ bias,
                                                     const float* __restrict__ Wout,
                                                     const float* __restrict__ bout,
                                                     float* __restrict__ out, int N) {
  int w = (blockIdx.x * 256 + threadIdx.x) >> 6;
  if (w >= N) return;
  int lane = threadIdx.x & 63;
  int g = lane >> 4, li = lane & 15;
  float acc[8];
  float di = agg_body_h4(P, rs, csrc, w, g, li, acc);
  float4 b0 = *(const float4*)(bias + li * 8);
  float4 b1 = *(const float4*)(bias + li * 8 + 4);
  float4 w0 = *(const float4*)(Wout + li * 8);
  float4 w1 = *(const float4*)(Wout + li * 8 + 4);
  float p = 0.f;
  p = fmaf(fmaxf(fmaf(di, acc[0], b0.x), 0.f), w0.x, p);
  p = fmaf(fmaxf(fmaf(di, acc[1], b0.y), 0.f), w0.y, p);
  p = fmaf(fmaxf(fmaf(di, acc[2], b0.z), 0.f), w0.z, p);
  p = fmaf(fmaxf(fmaf(di, acc[3], b0.w), 0.f), w0.w, p);
  p = fmaf(fmaxf(fmaf(di, acc[4], b1.x), 0.f), w1.x, p);
  p = fmaf(fmaxf(fmaf(di, acc[5], b1.y), 0.f), w1.y, p);
  p = fmaf(fmaxf(fmaf(di, acc[6], b1.z), 0.f), w1.z, p);
  p = fmaf(fmaxf(fmaf(di, acc[7], b1.w), 0.f), w1.w, p);
  p += __shfl_down(p, 8, 64);
  p += __shfl_down(p, 4, 64);
  p += __shfl_down(p, 2, 64);
  p += __shfl_down(p, 1, 64);
  if (lane == 0) out[w] = p + bout[0];
}

// ---------------- launch ----------------

extern "C" void kernel_launch(void* const* d_in, const int* in_sizes, int n_in,
                              void* d_out, int out_size, void* d_ws, size_t ws_size,
                              hipStream_t stream) {
  const float* x    = (const float*)d_in[0];
  const int*   ei   = (const int*)d_in[1];
  const float* W1   = (const float*)d_in[2];
  const float* b1   = (const float*)d_in[3];
  const float* W2   = (const float*)d_in[4];
  const float* b2   = (const float*)d_in[5];
  const float* Wout = (const float*)d_in[6];
  const float* bout = (const float*)d_in[7];
  float* out = (float*)d_out;

  const int N = in_sizes[0] / NFEAT;
  const int E = in_sizes[1] / 2;
  const int* src = ei;
  const int* dst = ei + E;
  const int NBUK = (N + 255) >> BUKSH;      // 256-node buckets (391, must be <= 512)
  const int nblk = (E + CHUNK - 1) / CHUNK; // sort blocks (196, <= 256 for co-residency)
  const int NG = (nblk + KG - 1) / KG;      // scan groups (7)

  char* ws = (char*)d_ws;
  size_t off = 0;
  auto alloc = [&](size_t bytes) -> char* {
    char* p = ws + off;
    off = align_up(off + bytes, 256);
    return p;
  };
  int*      gh    = (int*)alloc((size_t)nblk * NBUK * 4);
  int*      psum  = (int*)alloc((size_t)NG * NBUK * 4);
  int*      rsB   = (int*)alloc((size_t)(NBUK + 1) * 4);
  int*      rs    = (int*)alloc((size_t)(N + 1) * 4);
  float*    dis   = (float*)alloc((size_t)N * 4);
  unsigned* ebuf  = (unsigned*)alloc((size_t)E * 4);
  int*      csrc  = (int*)alloc((size_t)E * 4);
  __half*   W1t   = (__half*)alloc((size_t)NFEAT * NFEAT * 2);
  __half*   W2t   = (__half*)alloc((size_t)NFEAT * NFEAT * 2);
  __half*   P1    = (__half*)alloc((size_t)N * NFEAT * 2);
  __half*   H     = (__half*)alloc((size_t)N * NFEAT * 2);
  (void)ws_size; (void)n_in; (void)out_size;

  // cooperative preprocessing: one dispatch, grid.sync between phases
  {
    int nbuk = NBUK, nbk = nblk, ng = NG, n = N, e = E;
    void* args[] = {
      (void*)&W1, (void*)&W2, (void*)&W1t, (void*)&W2t,
      (void*)&src, (void*)&dst,
      (void*)&gh, (void*)&psum, (void*)&rsB, (void*)&rs, (void*)&dis,
      (void*)&ebuf, (void*)&csrc,
      (void*)&nbuk, (void*)&nbk, (void*)&ng, (void*)&n, (void*)&e,
    };
    hipLaunchCooperativeKernel((const void*)k_prep, dim3(nblk), dim3(512),
                               args, 768 * sizeof(int), stream);
  }

  k_gemm<float><<<(N + 63) / 64, 256, 0, stream>>>(x, W1t, dis, P1, N);
  k_agg_relu<<<(N + 3) / 4, 256, 0, stream>>>(P1, rs, csrc, b1, H, N);
  k_gemm<__half><<<(N + 63) / 64, 256, 0, stream>>>(H, W2t, dis, P1, N);
  k_agg_readout<<<(N + 3) / 4, 256, 0, stream>>>(P1, rs, csrc, b2, Wout, bout, out, N);
}

// Round 16
// 211.990 us; speedup vs baseline: 1.4799x; 1.4799x over previous
//
#include <hip/hip_runtime.h>
#include <hip/hip_fp16.h>
#include <type_traits>

#define NFEAT 128
// Packed bucket entry: (dst & 255) << 17 | src  (src < 2^17, bucket-local dst 8 bits)
#define SRC_BITS 17
#define SRC_MASK ((1u << SRC_BITS) - 1u)
#define BUKSH 8        // 256-node buckets
#define CHUNK 8192     // edges per sort block
#define STHREADS 512   // threads for hist/scatter/fill
#define KG 32          // sort blocks per scan group

using f16x8 = __attribute__((ext_vector_type(8))) _Float16;
using f32x4 = __attribute__((ext_vector_type(4))) float;

static inline size_t align_up(size_t x, size_t a) { return (x + a - 1) & ~(a - 1); }

// ---------------- preprocessing: atomic-free counting sort ----------------

// histogram + (blocks 0..31) fp16 weight transpose fused
__global__ __launch_bounds__(STHREADS) void k_hist(const int* __restrict__ dst,
                                                   int* __restrict__ gh,
                                                   const float* __restrict__ W1,
                                                   const float* __restrict__ W2,
                                                   __half* __restrict__ W1t,
                                                   __half* __restrict__ W2t,
                                                   int NBUK, int E) {
  extern __shared__ int h[];
  // fused weight transpose: 32 blocks x 512 thr x 2 elems = 32768 items
  if (blockIdx.x < 32) {
    int g = blockIdx.x * 1024 + threadIdx.x * 2;
    int m = g >> 14;
    const float* W = m ? W2 : W1;
    __half* Wt = m ? W2t : W1t;
    int oo = g & 16383;
    #pragma unroll
    for (int j = 0; j < 2; ++j) {
      int cdst = (oo + j) >> 7, rdst = (oo + j) & 127;
      Wt[oo + j] = __float2half(W[rdst * 128 + cdst]);
    }
  }
  for (int i = threadIdx.x; i < NBUK; i += STHREADS) h[i] = 0;
  __syncthreads();
  int base = blockIdx.x * CHUNK;
  int end = min(base + CHUNK, E);
  for (int e = base + threadIdx.x; e < end; e += STHREADS)
    atomicAdd(&h[dst[e] >> BUKSH], 1);
  __syncthreads();
  int* out = gh + (size_t)blockIdx.x * NBUK;
  for (int i = threadIdx.x; i < NBUK; i += STHREADS) out[i] = h[i];
}

// hierarchical block-prefix: pass 1 — within-group (KG blocks) prefix per bucket
__global__ __launch_bounds__(256) void k_colscan_part(int* __restrict__ gh,
                                                      int* __restrict__ psum,
                                                      int NBUK, int nblk) {
  int b = blockIdx.y * 256 + threadIdx.x;
  if (b >= NBUK) return;
  int kg = blockIdx.x;
  int k0 = kg * KG, k1 = min(k0 + KG, nblk);
  int run = 0;
  for (int k = k0; k < k1; ++k) {
    int idx = k * NBUK + b;
    int c = gh[idx];
    gh[idx] = run;
    run += c;
  }
  psum[kg * NBUK + b] = run;
}

// pass 2 + bucket-base scan fused (requires NBUK <= 512; NBUK=391 here)
__global__ __launch_bounds__(512) void k_colscan_fix2(int* __restrict__ psum,
                                                      int* __restrict__ rsB,
                                                      int NBUK, int NG, int E) {
  __shared__ int sd[512];
  int b = threadIdx.x;
  int tot = 0;
  if (b < NBUK) {
    int run = 0;
    for (int kg = 0; kg < NG; ++kg) {
      int idx = kg * NBUK + b;
      int c = psum[idx];
      psum[idx] = run;
      run += c;
    }
    tot = run;
  }
  sd[b] = tot;
  __syncthreads();
  for (int off = 1; off < 512; off <<= 1) {
    int t = (b >= off) ? sd[b - off] : 0;
    __syncthreads();
    sd[b] += t;
    __syncthreads();
  }
  if (b < NBUK) rsB[b] = sd[b] - tot;  // exclusive prefix
  if (b == 0) rsB[NBUK] = E;
}

// scatter packed (dst&255)<<17|src to bucket-sorted ebuf; LDS cursors, no global atomics
__global__ __launch_bounds__(STHREADS) void k_scatter(const int* __restrict__ src,
                                                      const int* __restrict__ dst,
                                                      const int* __restrict__ gh,
                                                      const int* __restrict__ psum,
                                                      const int* __restrict__ rsB,
                                                      unsigned* __restrict__ ebuf,
                                                      int NBUK, int E) {
  extern __shared__ int cur[];
  const int* g = gh + (size_t)blockIdx.x * NBUK;
  const int* p = psum + (size_t)(blockIdx.x / KG) * NBUK;
  for (int i = threadIdx.x; i < NBUK; i += STHREADS) cur[i] = rsB[i] + p[i] + g[i];
  __syncthreads();
  int base = blockIdx.x * CHUNK;
  int end = min(base + CHUNK, E);
  for (int e = base + threadIdx.x; e < end; e += STHREADS) {
    int d = dst[e];
    int pos = atomicAdd(&cur[d >> BUKSH], 1);
    ebuf[pos] = (unsigned)src[e] | ((unsigned)(d & 255) << SRC_BITS);
  }
}

// per-bucket CSR build (256 nodes/bucket, 512 threads): LDS histogram -> rs + dis, cursors -> csrc
__global__ __launch_bounds__(STHREADS) void k_fill3(const unsigned* __restrict__ ebuf,
                                                    const int* __restrict__ rsB,
                                                    int* __restrict__ rs,
                                                    float* __restrict__ dis,
                                                    int* __restrict__ csrc, int N) {
  __shared__ int hist[256];
  __shared__ int curs[256];
  __shared__ int sd[256];
  int b = blockIdx.x;
  int node0 = b << BUKSH;
  int nn = min(256, N - node0);
  int base = rsB[b], end = rsB[b + 1];
  int tid = threadIdx.x;
  if (tid < 256) hist[tid] = 0;
  __syncthreads();
  for (int e = base + tid; e < end; e += STHREADS)
    atomicAdd(&hist[ebuf[e] >> SRC_BITS], 1);
  __syncthreads();
  if (tid < 256) sd[tid] = hist[tid];
  __syncthreads();
  for (int off = 1; off < 256; off <<= 1) {
    int t = 0;
    if (tid < 256 && tid >= off) t = sd[tid - off];
    __syncthreads();
    if (tid < 256) sd[tid] += t;
    __syncthreads();
  }
  if (tid < 256) {
    int c = hist[tid];
    int start = base + sd[tid] - c;  // exclusive prefix
    curs[tid] = start;
    hist[tid] = start;
  }
  __syncthreads();
  if (tid < nn) {
    int start = hist[tid];
    int nxt = (tid == nn - 1) ? end : hist[tid + 1];
    rs[node0 + tid] = start;
    dis[node0 + tid] = rsqrtf((float)(nxt - start) + 1.0f);
  }
  if (tid == 0) rs[node0 + nn] = end;  // rs[N]=E on last bucket; benign dup otherwise
  for (int e = base + tid; e < end; e += STHREADS) {
    unsigned u = ebuf[e];
    int pos = atomicAdd(&curs[u >> SRC_BITS], 1);
    csrc[pos] = (int)(u & SRC_MASK);
  }
}

// ---------------- MFMA GEMM: P[N x128] = dis[i]*(X @ W), fp16 frag, fp32 acc ----------------

#define XS_LD 136  // halves; 272B row stride -> 2-way (free) bank aliasing on b128

template <typename T>
__global__ __launch_bounds__(256) void k_gemm(const T* __restrict__ X,
                                              const __half* __restrict__ Wt,
                                              const float* __restrict__ dis,
                                              __half* __restrict__ P, int N) {
  __shared__ __half Xs[64 * XS_LD];
  __shared__ __half Ws[128 * XS_LD];
  const int tid = threadIdx.x;
  const int wave = tid >> 6, lane = tid & 63;
  const int l15 = lane & 15, g = lane >> 4;
  const int rowBase = blockIdx.x * 64;

  #pragma unroll
  for (int it = 0; it < 8; ++it) {
    int q = it * 256 + tid;
    int r = q >> 4, c = (q & 15) * 8;
    *(int4*)&Ws[r * XS_LD + c] = *(const int4*)(Wt + r * 128 + c);
  }
  if constexpr (std::is_same_v<T, float>) {
    #pragma unroll
    for (int it = 0; it < 8; ++it) {
      int q = it * 256 + tid;
      int r = q >> 5, c = (q & 31) * 4;
      int gr = rowBase + r;
      float4 v = make_float4(0.f, 0.f, 0.f, 0.f);
      if (gr < N) v = *(const float4*)(X + (size_t)gr * NFEAT + c);
      __half2 pk[2];
      pk[0] = __floats2half2_rn(v.x, v.y);
      pk[1] = __floats2half2_rn(v.z, v.w);
      *(uint2*)&Xs[r * XS_LD + c] = *(uint2*)pk;
    }
  } else {
    #pragma unroll
    for (int it = 0; it < 4; ++it) {
      int q = it * 256 + tid;
      int r = q >> 4, c = (q & 15) * 8;
      int gr = rowBase + r;
      int4 v = make_int4(0, 0, 0, 0);
      if (gr < N) v = *(const int4*)(X + (size_t)gr * NFEAT + c);
      *(int4*)&Xs[r * XS_LD + c] = v;
    }
  }
  __syncthreads();

  f32x4 acc[4][2];
  #pragma unroll
  for (int rt = 0; rt < 4; ++rt) {
    acc[rt][0] = (f32x4)(0.f);
    acc[rt][1] = (f32x4)(0.f);
  }
  const int koff = g * 8;
  const int c0 = (wave * 2) * 16 + l15;
  const int c1 = (wave * 2 + 1) * 16 + l15;

  #pragma unroll
  for (int ks = 0; ks < 4; ++ks) {
    int kb = ks * 32 + koff;
    f16x8 b0 = *(const f16x8*)&Ws[c0 * XS_LD + kb];
    f16x8 b1 = *(const f16x8*)&Ws[c1 * XS_LD + kb];
    #pragma unroll
    for (int rt = 0; rt < 4; ++rt) {
      f16x8 a = *(const f16x8*)&Xs[(rt * 16 + l15) * XS_LD + kb];
      acc[rt][0] = __builtin_amdgcn_mfma_f32_16x16x32_f16(a, b0, acc[rt][0], 0, 0, 0);
      acc[rt][1] = __builtin_amdgcn_mfma_f32_16x16x32_f16(a, b1, acc[rt][1], 0, 0, 0);
    }
  }

  const int colb = wave * 32 + l15;
  #pragma unroll
  for (int rt = 0; rt < 4; ++rt) {
    #pragma unroll
    for (int r = 0; r < 4; ++r) {
      int row = rowBase + rt * 16 + g * 4 + r;
      if (row < N) {
        float di = dis[row];
        P[(size_t)row * NFEAT + colb]      = __float2half(di * acc[rt][0][r]);
        P[(size_t)row * NFEAT + colb + 16] = __float2half(di * acc[rt][1][r]);
      }
    }
  }
}

// ---------------- aggregation: one wave/node, 4 groups x 16 lanes, 4 edges in flight ----------------

__device__ __forceinline__ float agg_body_h4(const __half* __restrict__ P,
                                             const int* __restrict__ rs,
                                             const int* __restrict__ csrc,
                                             int w, int g, int li, float facc[8]) {
  int e0 = rs[w], e1 = rs[w + 1];
  float di = rsqrtf((float)(e1 - e0) + 1.0f);
  __half2 a0 = __float2half2_rn(0.f), a1 = a0, a2 = a0, a3 = a0;
  __half2 c0 = a0, c1 = a0, c2 = a0, c3 = a0;
  if (g == 0) {  // self loop
    int4 raw = *(const int4*)(P + (size_t)w * NFEAT + li * 8);
    const __half2* h2 = (const __half2*)&raw;
    a0 = h2[0]; a1 = h2[1]; a2 = h2[2]; a3 = h2[3];
  }
  const int lastc = max(e1 - 1, 0);
  int e = e0 + g;
  int s0 = csrc[min(e, lastc)];
  int s1 = csrc[min(e + 4, lastc)];
  int s2 = csrc[min(e + 8, lastc)];
  int s3 = csrc[min(e + 12, lastc)];
  while (e + 12 < e1) {
    int4 r0 = *(const int4*)(P + (size_t)s0 * NFEAT + li * 8);
    int4 r1 = *(const int4*)(P + (size_t)s1 * NFEAT + li * 8);
    int4 r2 = *(const int4*)(P + (size_t)s2 * NFEAT + li * 8);
    int4 r3 = *(const int4*)(P + (size_t)s3 * NFEAT + li * 8);
    e += 16;
    s0 = csrc[min(e, lastc)];
    s1 = csrc[min(e + 4, lastc)];
    s2 = csrc[min(e + 8, lastc)];
    s3 = csrc[min(e + 12, lastc)];
    const __half2* h0 = (const __half2*)&r0;
    const __half2* h1 = (const __half2*)&r1;
    const __half2* h2 = (const __half2*)&r2;
    const __half2* h3 = (const __half2*)&r3;
    a0 = __hadd2(a0, h0[0]); a1 = __hadd2(a1, h0[1]);
    a2 = __hadd2(a2, h0[2]); a3 = __hadd2(a3, h0[3]);
    c0 = __hadd2(c0, h1[0]); c1 = __hadd2(c1, h1[1]);
    c2 = __hadd2(c2, h1[2]); c3 = __hadd2(c3, h1[3]);
    a0 = __hadd2(a0, h2[0]); a1 = __hadd2(a1, h2[1]);
    a2 = __hadd2(a2, h2[2]); a3 = __hadd2(a3, h2[3]);
    c0 = __hadd2(c0, h3[0]); c1 = __hadd2(c1, h3[1]);
    c2 = __hadd2(c2, h3[2]); c3 = __hadd2(c3, h3[3]);
  }
  if (e < e1) {
    int4 r = *(const int4*)(P + (size_t)s0 * NFEAT + li * 8);
    const __half2* h = (const __half2*)&r;
    a0 = __hadd2(a0, h[0]); a1 = __hadd2(a1, h[1]);
    a2 = __hadd2(a2, h[2]); a3 = __hadd2(a3, h[3]);
    e += 4;
  }
  if (e < e1) {
    int4 r = *(const int4*)(P + (size_t)s1 * NFEAT + li * 8);
    const __half2* h = (const __half2*)&r;
    c0 = __hadd2(c0, h[0]); c1 = __hadd2(c1, h[1]);
    c2 = __hadd2(c2, h[2]); c3 = __hadd2(c3, h[3]);
    e += 4;
  }
  if (e < e1) {
    int4 r = *(const int4*)(P + (size_t)s2 * NFEAT + li * 8);
    const __half2* h = (const __half2*)&r;
    a0 = __hadd2(a0, h[0]); a1 = __hadd2(a1, h[1]);
    a2 = __hadd2(a2, h[2]); a3 = __hadd2(a3, h[3]);
  }
  a0 = __hadd2(a0, c0); a1 = __hadd2(a1, c1);
  a2 = __hadd2(a2, c2); a3 = __hadd2(a3, c3);
  float2 f0 = __half22float2(a0), f1 = __half22float2(a1);
  float2 f2 = __half22float2(a2), f3 = __half22float2(a3);
  facc[0] = f0.x; facc[1] = f0.y; facc[2] = f1.x; facc[3] = f1.y;
  facc[4] = f2.x; facc[5] = f2.y; facc[6] = f3.x; facc[7] = f3.y;
  #pragma unroll
  for (int j = 0; j < 8; ++j) {
    float v = facc[j];
    v += __shfl_xor(v, 16, 64);
    v += __shfl_xor(v, 32, 64);
    facc[j] = v;
  }
  return di;
}

__global__ __launch_bounds__(256) void k_agg_relu(const __half* __restrict__ P,
                                                  const int* __restrict__ rs,
                                                  const int* __restrict__ csrc,
                                                  const float* __restrict__ bias,
                                                  __half* __restrict__ Hout, int N) {
  int w = (blockIdx.x * 256 + threadIdx.x) >> 6;
  if (w >= N) return;
  int lane = threadIdx.x & 63;
  int g = lane >> 4, li = lane & 15;
  float acc[8];
  float di = agg_body_h4(P, rs, csrc, w, g, li, acc);
  if (g == 0) {
    float4 b0 = *(const float4*)(bias + li * 8);
    float4 b1 = *(const float4*)(bias + li * 8 + 4);
    __half2 o[4];
    o[0] = __floats2half2_rn(fmaxf(fmaf(di, acc[0], b0.x), 0.f),
                             fmaxf(fmaf(di, acc[1], b0.y), 0.f));
    o[1] = __floats2half2_rn(fmaxf(fmaf(di, acc[2], b0.z), 0.f),
                             fmaxf(fmaf(di, acc[3], b0.w), 0.f));
    o[2] = __floats2half2_rn(fmaxf(fmaf(di, acc[4], b1.x), 0.f),
                             fmaxf(fmaf(di, acc[5], b1.y), 0.f));
    o[3] = __floats2half2_rn(fmaxf(fmaf(di, acc[6], b1.z), 0.f),
                             fmaxf(fmaf(di, acc[7], b1.w), 0.f));
    *(int4*)(Hout + (size_t)w * NFEAT + li * 8) = *(const int4*)o;
  }
}

__global__ __launch_bounds__(256) void k_agg_readout(const __half* __restrict__ P,
                                                     const int* __restrict__ rs,
                                                     const int* __restrict__ csrc,
                                                     const float* __restrict__ bias,
                                                     const float* __restrict__ Wout,
                                                     const float* __restrict__ bout,
                                                     float* __restrict__ out, int N) {
  int w = (blockIdx.x * 256 + threadIdx.x) >> 6;
  if (w >= N) return;
  int lane = threadIdx.x & 63;
  int g = lane >> 4, li = lane & 15;
  float acc[8];
  float di = agg_body_h4(P, rs, csrc, w, g, li, acc);
  float4 b0 = *(const float4*)(bias + li * 8);
  float4 b1 = *(const float4*)(bias + li * 8 + 4);
  float4 w0 = *(const float4*)(Wout + li * 8);
  float4 w1 = *(const float4*)(Wout + li * 8 + 4);
  float p = 0.f;
  p = fmaf(fmaxf(fmaf(di, acc[0], b0.x), 0.f), w0.x, p);
  p = fmaf(fmaxf(fmaf(di, acc[1], b0.y), 0.f), w0.y, p);
  p = fmaf(fmaxf(fmaf(di, acc[2], b0.z), 0.f), w0.z, p);
  p = fmaf(fmaxf(fmaf(di, acc[3], b0.w), 0.f), w0.w, p);
  p = fmaf(fmaxf(fmaf(di, acc[4], b1.x), 0.f), w1.x, p);
  p = fmaf(fmaxf(fmaf(di, acc[5], b1.y), 0.f), w1.y, p);
  p = fmaf(fmaxf(fmaf(di, acc[6], b1.z), 0.f), w1.z, p);
  p = fmaf(fmaxf(fmaf(di, acc[7], b1.w), 0.f), w1.w, p);
  p += __shfl_down(p, 8, 64);
  p += __shfl_down(p, 4, 64);
  p += __shfl_down(p, 2, 64);
  p += __shfl_down(p, 1, 64);
  if (lane == 0) out[w] = p + bout[0];
}

// ---------------- launch ----------------

extern "C" void kernel_launch(void* const* d_in, const int* in_sizes, int n_in,
                              void* d_out, int out_size, void* d_ws, size_t ws_size,
                              hipStream_t stream) {
  const float* x    = (const float*)d_in[0];
  const int*   ei   = (const int*)d_in[1];
  const float* W1   = (const float*)d_in[2];
  const float* b1   = (const float*)d_in[3];
  const float* W2   = (const float*)d_in[4];
  const float* b2   = (const float*)d_in[5];
  const float* Wout = (const float*)d_in[6];
  const float* bout = (const float*)d_in[7];
  float* out = (float*)d_out;

  const int N = in_sizes[0] / NFEAT;
  const int E = in_sizes[1] / 2;
  const int* src = ei;
  const int* dst = ei + E;
  const int NBUK = (N + 255) >> BUKSH;      // 256-node buckets (391, must be <= 512)
  const int nblk = (E + CHUNK - 1) / CHUNK; // sort blocks (196)
  const int NG = (nblk + KG - 1) / KG;      // scan groups (7)

  char* ws = (char*)d_ws;
  size_t off = 0;
  auto alloc = [&](size_t bytes) -> char* {
    char* p = ws + off;
    off = align_up(off + bytes, 256);
    return p;
  };
  int*      gh    = (int*)alloc((size_t)nblk * NBUK * 4);
  int*      psum  = (int*)alloc((size_t)NG * NBUK * 4);
  int*      rsB   = (int*)alloc((size_t)(NBUK + 1) * 4);
  int*      rs    = (int*)alloc((size_t)(N + 1) * 4);
  float*    dis   = (float*)alloc((size_t)N * 4);
  unsigned* ebuf  = (unsigned*)alloc((size_t)E * 4);
  int*      csrc  = (int*)alloc((size_t)E * 4);
  __half*   W1t   = (__half*)alloc((size_t)NFEAT * NFEAT * 2);
  __half*   W2t   = (__half*)alloc((size_t)NFEAT * NFEAT * 2);
  __half*   P1    = (__half*)alloc((size_t)N * NFEAT * 2);
  __half*   H     = (__half*)alloc((size_t)N * NFEAT * 2);
  (void)ws_size; (void)n_in; (void)out_size;

  const size_t ldsBuk = (size_t)NBUK * 4;
  const int bukBlks = (NBUK + 255) / 256;  // 2

  k_hist<<<nblk, STHREADS, ldsBuk, stream>>>(dst, gh, W1, W2, W1t, W2t, NBUK, E);
  k_colscan_part<<<dim3(NG, bukBlks), 256, 0, stream>>>(gh, psum, NBUK, nblk);
  k_colscan_fix2<<<1, 512, 0, stream>>>(psum, rsB, NBUK, NG, E);
  k_scatter<<<nblk, STHREADS, ldsBuk, stream>>>(src, dst, gh, psum, rsB, ebuf, NBUK, E);
  k_fill3<<<NBUK, STHREADS, 0, stream>>>(ebuf, rsB, rs, dis, csrc, N);

  k_gemm<float><<<(N + 63) / 64, 256, 0, stream>>>(x, W1t, dis, P1, N);
  k_agg_relu<<<(N + 3) / 4, 256, 0, stream>>>(P1, rs, csrc, b1, H, N);
  k_gemm<__half><<<(N + 63) / 64, 256, 0, stream>>>(H, W2t, dis, P1, N);
  k_agg_readout<<<(N + 3) / 4, 256, 0, stream>>>(P1, rs, csrc, b2, Wout, bout, out, N);
}